// Round 20
// baseline (63.198 us; speedup 1.0000x reference)
//
#include <hip/hip_runtime.h>
#include <math.h>

#define Hh 512
#define Nn 64
#define Ll 2048
#define Bb 8

typedef float f32x4 __attribute__((ext_vector_type(4)));
typedef __bf16 bf16x8 __attribute__((ext_vector_type(8)));

__device__ __forceinline__ unsigned short f2b(float x) {
  unsigned u = __builtin_bit_cast(unsigned, x);
  u += 0x7FFFu + ((u >> 16) & 1u);
  return (unsigned short)(u >> 16);
}
__device__ __forceinline__ float b2f(unsigned short b) {
  unsigned u = ((unsigned)b) << 16;
  return __builtin_bit_cast(float, u);
}

union BF8 {
  unsigned short us[8];
  bf16x8 v;
  uint4 q;
};

__device__ __forceinline__ uint4 cvt8q(const float* p) {
  float4 a = *(const float4*)p;
  float4 b = *(const float4*)(p + 4);
  BF8 o;
  o.us[0] = f2b(a.x); o.us[1] = f2b(a.y); o.us[2] = f2b(a.z); o.us[3] = f2b(a.w);
  o.us[4] = f2b(b.x); o.us[5] = f2b(b.y); o.us[6] = f2b(b.z); o.us[7] = f2b(b.w);
  return o.q;
}

// gelu tanh-form: y * sigmoid(1.5957691216*(y + 0.044715*y^3)); |err| < 5e-4
__device__ __forceinline__ float gelu_f(float y) {
  float t = y * y;
  float p = y * fmaf(0.0713548162726f, t, 1.59576912161f);
  float e = __expf(-p);
  return y / (1.0f + e);
}

// ---------------------------------------------------------------------------
// prep_fused (unchanged from round 17)
// ---------------------------------------------------------------------------
__global__ __launch_bounds__(512) void prep_kernel(
    const float* __restrict__ C_ri, const float* __restrict__ log_dt,
    const float* __restrict__ A_ri, const float* __restrict__ W,
    unsigned short* __restrict__ A1, unsigned short* __restrict__ A2,
    float* __restrict__ lamQ, unsigned short* __restrict__ Wimg) {
  int tid = threadIdx.x;
  if (blockIdx.x >= 512) {
    int id = (blockIdx.x - 512) * 512 + tid;
    int slot = id & 3, row = (id >> 2) & 127, kt = (id >> 9) & 15, ot = id >> 13;
    int o = (row < 64) ? (ot * 64 + row) : (512 + ot * 64 + row - 64);
    uint4 v = cvt8q(W + (size_t)o * 512 + kt * 32 + slot * 8);
    int sp = slot ^ ((row >> 1) & 3);
    *(uint4*)((char*)Wimg + (((size_t)ot * 16 + kt) * 8192) + row * 64 + sp * 16) = v;
    return;
  }
  __shared__ char sm[49152];
  __shared__ float kqs[64];
  __shared__ float kpart[8][64];
  float* kt = (float*)sm;
  char* A1s = sm;
  char* A2s = sm + 16384;
  int h = blockIdx.x;
  int n = tid & 63, part = tid >> 6;

  float dt = expf(log_dt[h]);
  float ar = A_ri[2 * n], ai = A_ri[2 * n + 1];
  float er = expf(dt * ar);
  float sn, cs;
  sincosf(dt * ai, &sn, &cs);
  float lr = er * cs, li = er * sn;
  float em1r = lr - 1.0f, em1i = li;
  float cr = C_ri[(h * 64 + n) * 2], ci = C_ri[(h * 64 + n) * 2 + 1];
  float numr = cr * em1r - ci * em1i;
  float numi = cr * em1i + ci * em1r;
  float den = ar * ar + ai * ai;
  float ctr = (numr * ar + numi * ai) / den;
  float cti = (numi * ar - numr * ai) / den;
  float l8r = lr, l8i = li;
#pragma unroll
  for (int s = 0; s < 3; ++s) {
    float t = l8r * l8r - l8i * l8i;
    l8i = 2.0f * l8r * l8i;
    l8r = t;
  }
  if (part == 0) {
    float qr = l8r, qi = l8i;
#pragma unroll
    for (int s = 0; s < 3; ++s) {
      float t = qr * qr - qi * qi;
      qi = 2.0f * qr * qi;
      qr = t;
    }
    lamQ[h * 128 + 2 * n] = qr;
    lamQ[h * 128 + 2 * n + 1] = qi;
  }
  float lpr = 1.0f, lpi = 0.0f;
  for (int s = 0; s < part; ++s) {
    float t = lpr * l8r - lpi * l8i;
    lpi = lpr * l8i + lpi * l8r;
    lpr = t;
  }
  int e0 = part * 8;
  {
    float vr = ctr * lpr - cti * lpi, vi = ctr * lpi + cti * lpr;
#pragma unroll
    for (int j = 0; j < 8; ++j) {
      kt[(e0 + j) * 64 + n] = vr;
      float t = vr * lr - vi * li;
      vi = vr * li + vi * lr;
      vr = t;
    }
  }
  __syncthreads();
  {
    float s = 0.0f;
#pragma unroll
    for (int j = 0; j < 8; ++j) s += kt[n * 64 + ((e0 + j + n) & 63)];
    kpart[part][n] = s;
  }
  __syncthreads();
  if (part == 0) {
    float s = 0.0f;
#pragma unroll
    for (int p2 = 0; p2 < 8; ++p2) s += kpart[p2][n];
    kqs[n] = 2.0f * s;
  }
  __syncthreads();
  {
    BF8 R0, I0;
    float vr = lpr, vi = lpi;
#pragma unroll
    for (int j = 0; j < 8; ++j) {
      int idx = 7 - j;
      R0.us[idx] = f2b(vr);
      I0.us[idx] = f2b(vi);
      float t = vr * lr - vi * li;
      vi = vr * li + vi * lr;
      vr = t;
    }
    int qlo = 56 - e0;
    int rowR = 2 * n, rowI = 2 * n + 1;
    *(uint4*)(A1s + ((rowR * 128 + 2 * qlo) ^ ((rowR & 7) << 4))) = R0.q;
    *(uint4*)(A1s + ((rowI * 128 + 2 * qlo) ^ ((rowI & 7) << 4))) = I0.q;
  }
  {
    float c1r = ctr * lr - cti * li, c1i = ctr * li + cti * lr;
    float wr = 2.0f * (c1r * lpr - c1i * lpi);
    float wi = 2.0f * (c1r * lpi + c1i * lpr);
#pragma unroll
    for (int j = 0; j < 8; ++j) {
      int t = e0 + j;
      *(unsigned*)(A2s + ((t * 512 + 128 + 4 * n) ^ ((t & 7) << 4))) =
          (unsigned)f2b(wr) | ((unsigned)f2b(-wi) << 16);
      float tm = wr * lr - wi * li;
      wi = wr * li + wi * lr;
      wr = tm;
    }
  }
  {
    int tau = n;
    BF8 o;
#pragma unroll
    for (int j = 0; j < 8; ++j) {
      int q = e0 + j;
      o.us[j] = (q <= tau) ? f2b(kqs[tau - q]) : (unsigned short)0;
    }
    *(uint4*)(A2s + ((tau * 512 + 2 * e0) ^ ((tau & 7) << 4))) = o.q;
  }
  __syncthreads();
#pragma unroll
  for (int i = 0; i < 2; ++i) {
    int byte = (i * 512 + tid) * 16;
    int row = byte >> 7;
    *(uint4*)((char*)A1 + (size_t)h * 16384 + byte) =
        *(const uint4*)(A1s + (byte ^ ((row & 7) << 4)));
  }
#pragma unroll
  for (int i = 0; i < 4; ++i) {
    int idx = i * 512 + tid;
    int row = idx >> 5;
    int byte = row * 512 + (idx & 31) * 16;
    *(uint4*)((char*)A2 + (size_t)h * 32768 + byte) =
        *(const uint4*)(A2s + (byte ^ ((row & 7) << 4)));
  }
}

// ---------------------------------------------------------------------------
// fused conv v3.1: identical math to round 14; grid transposed to (4, Hh)
// so the 4 column-quarters of one h are dispatch-adjacent (same XCD L2
// for the shared 48KB A1/A2 panels).
// ---------------------------------------------------------------------------
__global__ __launch_bounds__(256, 5) void fused_conv_kernel(
    const float* __restrict__ u, const unsigned short* __restrict__ A1,
    const unsigned short* __restrict__ A2, const float* __restrict__ lamQ,
    const float* __restrict__ Dv, unsigned short* __restrict__ gy) {
  __shared__ char SXb[16384];
  __shared__ char Ub[8192];
  __shared__ float2 sX16[2][64];
  int h = blockIdx.y;
  int bs = blockIdx.x * 2;
  int tid = threadIdx.x;
  int w = tid >> 6, lane = tid & 63, lg = lane >> 4, l15 = lane & 15;

  {
    int row = tid >> 2, k0 = (tid & 3) * 16;
    int b = bs + (row >> 5), c = row & 31;
    const float* up = u + ((size_t)(b * Hh + h)) * Ll + c * 64 + k0;
    uint4 v0 = cvt8q(up), v1 = cvt8q(up + 8);
    int base = row * 128 + k0 * 2;
    int swz = (row & 7) << 4;
    *(uint4*)(Ub + (base ^ swz)) = v0;
    *(uint4*)(Ub + ((base + 16) ^ swz)) = v1;
  }
  bf16x8 a1f[2][2];
#pragma unroll
  for (int i = 0; i < 2; ++i) {
    int row = (2 * w + i) * 16 + l15;
#pragma unroll
    for (int kb = 0; kb < 2; ++kb)
      a1f[i][kb] = *(const bf16x8*)(A1 + ((size_t)h * 128 + row) * 64 + kb * 32 + lg * 8);
  }
  __syncthreads();

#pragma unroll
  for (int ct = 0; ct < 4; ++ct) {
    int bc = ct * 16 + l15;
    bf16x8 bu[2];
#pragma unroll
    for (int kb = 0; kb < 2; ++kb)
      bu[kb] = *(const bf16x8*)(Ub + ((bc * 128 + kb * 64 + lg * 16) ^ ((bc & 7) << 4)));
#pragma unroll
    for (int i = 0; i < 2; ++i) {
      f32x4 acc = {0.f, 0.f, 0.f, 0.f};
      acc = __builtin_amdgcn_mfma_f32_16x16x32_bf16(a1f[i][0], bu[0], acc, 0, 0, 0);
      acc = __builtin_amdgcn_mfma_f32_16x16x32_bf16(a1f[i][1], bu[1], acc, 0, 0, 0);
      int n2q = (2 * w + i) * 16 + lg * 4;
      uint2 pk;
      pk.x = f2b(acc[0]) | ((unsigned)f2b(acc[1]) << 16);
      pk.y = f2b(acc[2]) | ((unsigned)f2b(acc[3]) << 16);
      *(uint2*)(SXb + ((bc * 256 + n2q * 2) ^ ((bc & 7) << 4))) = pk;
    }
  }
  __syncthreads();

  bf16x8 a2f[6];
  int rowA = w * 16 + l15;
#pragma unroll
  for (int kb = 0; kb < 6; ++kb)
    a2f[kb] = *(const bf16x8*)(A2 + ((size_t)h * 64 + rowA) * 256 + kb * 32 + lg * 8);

  int nn = tid & 63, bpart = tid >> 6;
  int rbloc = bpart >> 1, rhalf = bpart & 1;
  float lqr = lamQ[h * 128 + 2 * nn], lqi = lamQ[h * 128 + 2 * nn + 1];
  {
    float Xr = 0.f, Xi = 0.f;
    int cbase = rbloc * 32 + rhalf * 16;
    for (int c = 0; c < 16; ++c) {
      int bc = cbase + c;
      int byte = (bc * 256 + 4 * nn) ^ ((bc & 7) << 4);
      unsigned ps = *(const unsigned*)(SXb + byte);
      *(unsigned*)(SXb + byte) = (unsigned)f2b(Xr) | ((unsigned)f2b(Xi) << 16);
      float Sr = b2f((unsigned short)(ps & 0xFFFF));
      float Si = b2f((unsigned short)(ps >> 16));
      float nXr = lqr * Xr - lqi * Xi + Sr;
      float nXi = lqr * Xi + lqi * Xr + Si;
      Xr = nXr;
      Xi = nXi;
    }
    if (rhalf == 0) sX16[rbloc][nn] = make_float2(Xr, Xi);
  }
  __syncthreads();
  if (rhalf) {
    float2 x16 = sX16[rbloc][nn];
    float cr = x16.x, ci = x16.y;
    int cbase = rbloc * 32 + 16;
#pragma unroll
    for (int c = 0; c < 16; ++c) {
      int bc = cbase + c;
      int byte = (bc * 256 + 4 * nn) ^ ((bc & 7) << 4);
      unsigned pv = *(const unsigned*)(SXb + byte);
      float vr = b2f((unsigned short)(pv & 0xFFFF)) + cr;
      float vi = b2f((unsigned short)(pv >> 16)) + ci;
      *(unsigned*)(SXb + byte) = (unsigned)f2b(vr) | ((unsigned)f2b(vi) << 16);
      float t = cr * lqr - ci * lqi;
      ci = cr * lqi + ci * lqr;
      cr = t;
    }
  }
  __syncthreads();

  float Dh = Dv[h];
  int t0 = w * 16 + lg * 4;
  f32x4 acc4[4];
  uint2 usk[4];
#pragma unroll
  for (int ct = 0; ct < 4; ++ct) {
    int bc = ct * 16 + l15;
    f32x4 acc = {0.f, 0.f, 0.f, 0.f};
#pragma unroll
    for (int kb = 0; kb < 2; ++kb) {
      bf16x8 bu = *(const bf16x8*)(Ub + ((bc * 128 + kb * 64 + lg * 16) ^ ((bc & 7) << 4)));
      acc = __builtin_amdgcn_mfma_f32_16x16x32_bf16(a2f[kb], bu, acc, 0, 0, 0);
    }
#pragma unroll
    for (int kb = 2; kb < 6; ++kb) {
      bf16x8 bx = *(const bf16x8*)(SXb + ((bc * 256 + ((kb - 2) * 32 + lg * 8) * 2) ^ ((bc & 7) << 4)));
      acc = __builtin_amdgcn_mfma_f32_16x16x32_bf16(a2f[kb], bx, acc, 0, 0, 0);
    }
    acc4[ct] = acc;
    usk[ct] = *(const uint2*)(Ub + ((bc * 128 + t0 * 2) ^ ((bc & 7) << 4)));
  }
  __syncthreads();

#pragma unroll
  for (int ct = 0; ct < 4; ++ct) {
    int bc = ct * 16 + l15;
    const unsigned short* up = (const unsigned short*)&usk[ct];
    unsigned short e[4];
#pragma unroll
    for (int r = 0; r < 4; ++r) {
      float y = fmaf(Dh, b2f(up[r]), acc4[ct][r]);
      e[r] = f2b(gelu_f(y));
    }
    uint2 pk;
    pk.x = e[0] | ((unsigned)e[1] << 16);
    pk.y = e[2] | ((unsigned)e[3] << 16);
    *(uint2*)(Ub + ((bc * 128 + t0 * 2) ^ ((bc & 7) << 4))) = pk;
  }
  __syncthreads();

#pragma unroll
  for (int i = 0; i < 2; ++i) {
    int j = tid + 256 * i;
    int row = j >> 3, q = j & 7;
    int byte = row * 128 + q * 16;
    uint4 v = *(const uint4*)(Ub + (byte ^ ((row & 7) << 4)));
    int b = bs + (row >> 5), c = row & 31;
    *(uint4*)(gy + ((size_t)(b * Hh + h)) * Ll + c * 64 + q * 8) = v;
  }
}

// ---------------------------------------------------------------------------
// GLU v8 (byte-exact revert to round 18 — best measured)
// ---------------------------------------------------------------------------
__global__ __launch_bounds__(512, 4) void glu_kernel(
    const unsigned short* __restrict__ Wimg, const unsigned short* __restrict__ gy,
    const float* __restrict__ bias, float* __restrict__ out) {
  __shared__ char sA[2][2][8192];   // [buf][otl]
  __shared__ char sB[2][8192];
  int lt = blockIdx.x;
  int oz = blockIdx.y;
  int b = lt >> 4, lseg = lt & 15;
  int t = threadIdx.x;
  int lane = t & 63, lg = lane >> 4, l15 = lane & 15;
  int w = t >> 6;
  int otl = w & 1;
  int ot = oz * 2 + otl;
  int wm = (w >> 2) & 1, wn = (w >> 1) & 1;
  int doB = (t < 256);
  int p = (t >> 4) & 15, cg = t & 15;
  const char* Abase0 = (const char*)Wimg + (size_t)(oz * 2) * 131072;
  const char* Abase1 = (const char*)Wimg + (size_t)(oz * 2 + 1) * 131072;
  const unsigned short* gybase = gy + (size_t)b * Hh * Ll + lseg * 128 + cg * 8 + 2 * p * Ll;

  int offA[2], offG[2];
#pragma unroll
  for (int mt = 0; mt < 2; ++mt) {
    int rA = wm * 32 + mt * 16 + l15;
    offA[mt] = rA * 64 + ((lg ^ ((rA >> 1) & 3)) << 4);
    int rG = rA + 64;
    offG[mt] = rG * 64 + ((lg ^ ((rG >> 1) & 3)) << 4);
  }
  int offB[4];
#pragma unroll
  for (int nt = 0; nt < 4; ++nt) {
    int rB = wn * 64 + nt * 16 + l15;
    int pr = ((rB >> 3) << 3) | ((rB & 7) ^ ((rB >> 3) & 7));
    offB[nt] = (lg << 11) + (pr << 4);
  }
  int offW[8];
#pragma unroll
  for (int j = 0; j < 8; ++j) {
    int pr = (cg << 3) | (j ^ (cg & 7));
    offW[j] = ((p >> 2) << 11) + (pr << 4) + ((p & 3) << 2);
  }

  f32x4 accA[2][4], accG[2][4];
#pragma unroll
  for (int mt = 0; mt < 2; ++mt)
#pragma unroll
    for (int nt = 0; nt < 4; ++nt) {
      accA[mt][nt] = (f32x4){0.f, 0.f, 0.f, 0.f};
      accG[mt][nt] = (f32x4){0.f, 0.f, 0.f, 0.f};
    }

  // prologue: stage kt=0 (A both ots via glds; B via reg+ds_write, waves 0-3)
  {
    __builtin_amdgcn_global_load_lds(Abase0 + t * 16, (char*)&sA[0][0][0] + t * 16, 16, 0, 0);
    __builtin_amdgcn_global_load_lds(Abase1 + t * 16, (char*)&sA[0][1][0] + t * 16, 16, 0, 0);
    if (doB) {
      BF8 r0, r1;
      r0.q = *(const uint4*)gybase;
      r1.q = *(const uint4*)(gybase + Ll);
#pragma unroll
      for (int j = 0; j < 8; ++j)
        *(unsigned*)(&sB[0][0] + offW[j]) =
            (unsigned)r0.us[j] | ((unsigned)r1.us[j] << 16);
    }
  }
  __syncthreads();

  for (int kt = 0; kt < 16; ++kt) {
    int cur = kt & 1;
    BF8 r0, r1;
    if (kt < 15) {
      __builtin_amdgcn_global_load_lds(Abase0 + (kt + 1) * 8192 + t * 16,
                                       (char*)&sA[cur ^ 1][0][0] + t * 16, 16, 0, 0);
      __builtin_amdgcn_global_load_lds(Abase1 + (kt + 1) * 8192 + t * 16,
                                       (char*)&sA[cur ^ 1][1][0] + t * 16, 16, 0, 0);
      if (doB) {
        r0.q = *(const uint4*)(gybase + (size_t)(kt + 1) * 32 * Ll);
        r1.q = *(const uint4*)(gybase + (size_t)(kt + 1) * 32 * Ll + Ll);
      }
    }
    const char* bufA = &sA[cur][otl][0];
    const char* bufB = &sB[cur][0];
    bf16x8 aA[2], aG[2], bB[4];
#pragma unroll
    for (int mt = 0; mt < 2; ++mt) {
      aA[mt] = *(const bf16x8*)(bufA + offA[mt]);
      aG[mt] = *(const bf16x8*)(bufA + offG[mt]);
    }
#pragma unroll
    for (int nt = 0; nt < 4; ++nt)
      bB[nt] = *(const bf16x8*)(bufB + offB[nt]);
#pragma unroll
    for (int mt = 0; mt < 2; ++mt)
#pragma unroll
      for (int nt = 0; nt < 4; ++nt) {
        accA[mt][nt] = __builtin_amdgcn_mfma_f32_16x16x32_bf16(bB[nt], aA[mt], accA[mt][nt], 0, 0, 0);
        accG[mt][nt] = __builtin_amdgcn_mfma_f32_16x16x32_bf16(bB[nt], aG[mt], accG[mt][nt], 0, 0, 0);
      }
    if (kt < 15 && doB) {
      char* db = &sB[cur ^ 1][0];
#pragma unroll
      for (int j = 0; j < 8; ++j)
        *(unsigned*)(db + offW[j]) =
            (unsigned)r0.us[j] | ((unsigned)r1.us[j] << 16);
    }
    __syncthreads();
  }

  // epilogue
#pragma unroll
  for (int mt = 0; mt < 2; ++mt) {
    int oA = ot * 64 + wm * 32 + mt * 16 + l15;
    float ba = bias[oA];
    float bg = bias[512 + oA];
    float* orow = out + ((size_t)(b * Hh) + oA) * Ll + lseg * 128 + wn * 64 + lg * 4;
#pragma unroll
    for (int nt = 0; nt < 4; ++nt) {
      float4 res;
      float* rp = (float*)&res;
#pragma unroll
      for (int r = 0; r < 4; ++r) {
        float a = accA[mt][nt][r] + ba;
        float g = accG[mt][nt][r] + bg;
        rp[r] = a * (1.0f / (1.0f + __expf(-g)));
      }
      *(float4*)(orow + nt * 16) = res;
    }
  }
}

// ---------------------------------------------------------------------------
extern "C" void kernel_launch(void* const* d_in, const int* in_sizes, int n_in,
                              void* d_out, int out_size, void* d_ws,
                              size_t ws_size, hipStream_t stream) {
  const float* u      = (const float*)d_in[0];
  const float* C_ri   = (const float*)d_in[1];
  const float* log_dt = (const float*)d_in[2];
  const float* D_v    = (const float*)d_in[3];
  const float* W      = (const float*)d_in[4];
  const float* bias   = (const float*)d_in[5];
  const float* A_ri   = (const float*)d_in[6];
  float* out = (float*)d_out;

  char* ws = (char*)d_ws;
  unsigned short* A1   = (unsigned short*)ws;                // 8 MB
  unsigned short* A2   = (unsigned short*)(ws + 8388608);    // 16 MB
  float*          lamQ = (float*)(ws + 25165824);            // 256 KB
  unsigned short* Wimg = (unsigned short*)(ws + 25427968);   // 1 MB
  unsigned short* gy   = (unsigned short*)(ws + 26476544);   // 16 MB

  prep_kernel<<<640, 512, 0, stream>>>(C_ri, log_dt, A_ri, W, A1, A2, lamQ, Wimg);
  fused_conv_kernel<<<dim3(4, Hh), 256, 0, stream>>>(u, A1, A2, lamQ, D_v, gy);
  glu_kernel<<<dim3(128, 4), 512, 0, stream>>>(Wimg, gy, bias, out);
}

// Round 21
// 59.582 us; speedup vs baseline: 1.0607x; 1.0607x over previous
//
#include <hip/hip_runtime.h>
#include <math.h>

#define Hh 512
#define Nn 64
#define Ll 2048
#define Bb 8

typedef float f32x4 __attribute__((ext_vector_type(4)));
typedef __bf16 bf16x8 __attribute__((ext_vector_type(8)));

__device__ __forceinline__ unsigned short f2b(float x) {
  unsigned u = __builtin_bit_cast(unsigned, x);
  u += 0x7FFFu + ((u >> 16) & 1u);
  return (unsigned short)(u >> 16);
}
__device__ __forceinline__ float b2f(unsigned short b) {
  unsigned u = ((unsigned)b) << 16;
  return __builtin_bit_cast(float, u);
}

union BF8 {
  unsigned short us[8];
  bf16x8 v;
  uint4 q;
};

__device__ __forceinline__ uint4 cvt8q(const float* p) {
  float4 a = *(const float4*)p;
  float4 b = *(const float4*)(p + 4);
  BF8 o;
  o.us[0] = f2b(a.x); o.us[1] = f2b(a.y); o.us[2] = f2b(a.z); o.us[3] = f2b(a.w);
  o.us[4] = f2b(b.x); o.us[5] = f2b(b.y); o.us[6] = f2b(b.z); o.us[7] = f2b(b.w);
  return o.q;
}

// gelu tanh-form: y * sigmoid(1.5957691216*(y + 0.044715*y^3)); |err| < 5e-4
__device__ __forceinline__ float gelu_f(float y) {
  float t = y * y;
  float p = y * fmaf(0.0713548162726f, t, 1.59576912161f);
  float e = __expf(-p);
  return y / (1.0f + e);
}

// ---------------------------------------------------------------------------
// prep_fused: blocks 0..511 = prep for h (8 parts x 8-step chains);
// blocks 512..639 = wcvt (W f32 -> Wimg image layout).
// ---------------------------------------------------------------------------
__global__ __launch_bounds__(512) void prep_kernel(
    const float* __restrict__ C_ri, const float* __restrict__ log_dt,
    const float* __restrict__ A_ri, const float* __restrict__ W,
    unsigned short* __restrict__ A1, unsigned short* __restrict__ A2,
    float* __restrict__ lamQ, unsigned short* __restrict__ Wimg) {
  int tid = threadIdx.x;
  if (blockIdx.x >= 512) {
    int id = (blockIdx.x - 512) * 512 + tid;
    int slot = id & 3, row = (id >> 2) & 127, kt = (id >> 9) & 15, ot = id >> 13;
    int o = (row < 64) ? (ot * 64 + row) : (512 + ot * 64 + row - 64);
    uint4 v = cvt8q(W + (size_t)o * 512 + kt * 32 + slot * 8);
    int sp = slot ^ ((row >> 1) & 3);
    *(uint4*)((char*)Wimg + (((size_t)ot * 16 + kt) * 8192) + row * 64 + sp * 16) = v;
    return;
  }
  __shared__ char sm[49152];
  __shared__ float kqs[64];
  __shared__ float kpart[8][64];
  float* kt = (float*)sm;
  char* A1s = sm;
  char* A2s = sm + 16384;
  int h = blockIdx.x;
  int n = tid & 63, part = tid >> 6;

  float dt = expf(log_dt[h]);
  float ar = A_ri[2 * n], ai = A_ri[2 * n + 1];
  float er = expf(dt * ar);
  float sn, cs;
  sincosf(dt * ai, &sn, &cs);
  float lr = er * cs, li = er * sn;
  float em1r = lr - 1.0f, em1i = li;
  float cr = C_ri[(h * 64 + n) * 2], ci = C_ri[(h * 64 + n) * 2 + 1];
  float numr = cr * em1r - ci * em1i;
  float numi = cr * em1i + ci * em1r;
  float den = ar * ar + ai * ai;
  float ctr = (numr * ar + numi * ai) / den;
  float cti = (numi * ar - numr * ai) / den;
  float l8r = lr, l8i = li;
#pragma unroll
  for (int s = 0; s < 3; ++s) {
    float t = l8r * l8r - l8i * l8i;
    l8i = 2.0f * l8r * l8i;
    l8r = t;
  }
  if (part == 0) {
    float qr = l8r, qi = l8i;
#pragma unroll
    for (int s = 0; s < 3; ++s) {
      float t = qr * qr - qi * qi;
      qi = 2.0f * qr * qi;
      qr = t;
    }
    lamQ[h * 128 + 2 * n] = qr;
    lamQ[h * 128 + 2 * n + 1] = qi;
  }
  float lpr = 1.0f, lpi = 0.0f;
  for (int s = 0; s < part; ++s) {
    float t = lpr * l8r - lpi * l8i;
    lpi = lpr * l8i + lpi * l8r;
    lpr = t;
  }
  int e0 = part * 8;
  {
    float vr = ctr * lpr - cti * lpi, vi = ctr * lpi + cti * lpr;
#pragma unroll
    for (int j = 0; j < 8; ++j) {
      kt[(e0 + j) * 64 + n] = vr;
      float t = vr * lr - vi * li;
      vi = vr * li + vi * lr;
      vr = t;
    }
  }
  __syncthreads();
  {
    float s = 0.0f;
#pragma unroll
    for (int j = 0; j < 8; ++j) s += kt[n * 64 + ((e0 + j + n) & 63)];
    kpart[part][n] = s;
  }
  __syncthreads();
  if (part == 0) {
    float s = 0.0f;
#pragma unroll
    for (int p2 = 0; p2 < 8; ++p2) s += kpart[p2][n];
    kqs[n] = 2.0f * s;
  }
  __syncthreads();
  {
    BF8 R0, I0;
    float vr = lpr, vi = lpi;
#pragma unroll
    for (int j = 0; j < 8; ++j) {
      int idx = 7 - j;
      R0.us[idx] = f2b(vr);
      I0.us[idx] = f2b(vi);
      float t = vr * lr - vi * li;
      vi = vr * li + vi * lr;
      vr = t;
    }
    int qlo = 56 - e0;
    int rowR = 2 * n, rowI = 2 * n + 1;
    *(uint4*)(A1s + ((rowR * 128 + 2 * qlo) ^ ((rowR & 7) << 4))) = R0.q;
    *(uint4*)(A1s + ((rowI * 128 + 2 * qlo) ^ ((rowI & 7) << 4))) = I0.q;
  }
  {
    float c1r = ctr * lr - cti * li, c1i = ctr * li + cti * lr;
    float wr = 2.0f * (c1r * lpr - c1i * lpi);
    float wi = 2.0f * (c1r * lpi + c1i * lpr);
#pragma unroll
    for (int j = 0; j < 8; ++j) {
      int t = e0 + j;
      *(unsigned*)(A2s + ((t * 512 + 128 + 4 * n) ^ ((t & 7) << 4))) =
          (unsigned)f2b(wr) | ((unsigned)f2b(-wi) << 16);
      float tm = wr * lr - wi * li;
      wi = wr * li + wi * lr;
      wr = tm;
    }
  }
  {
    int tau = n;
    BF8 o;
#pragma unroll
    for (int j = 0; j < 8; ++j) {
      int q = e0 + j;
      o.us[j] = (q <= tau) ? f2b(kqs[tau - q]) : (unsigned short)0;
    }
    *(uint4*)(A2s + ((tau * 512 + 2 * e0) ^ ((tau & 7) << 4))) = o.q;
  }
  __syncthreads();
#pragma unroll
  for (int i = 0; i < 2; ++i) {
    int byte = (i * 512 + tid) * 16;
    int row = byte >> 7;
    *(uint4*)((char*)A1 + (size_t)h * 16384 + byte) =
        *(const uint4*)(A1s + (byte ^ ((row & 7) << 4)));
  }
#pragma unroll
  for (int i = 0; i < 4; ++i) {
    int idx = i * 512 + tid;
    int row = idx >> 5;
    int byte = row * 512 + (idx & 31) * 16;
    *(uint4*)((char*)A2 + (size_t)h * 32768 + byte) =
        *(const uint4*)(A2s + (byte ^ ((row & 7) << 4)));
  }
}

// ---------------------------------------------------------------------------
// fused conv v3 (round-14 version, grid (Hh, 4) — best measured)
// ---------------------------------------------------------------------------
__global__ __launch_bounds__(256, 5) void fused_conv_kernel(
    const float* __restrict__ u, const unsigned short* __restrict__ A1,
    const unsigned short* __restrict__ A2, const float* __restrict__ lamQ,
    const float* __restrict__ Dv, unsigned short* __restrict__ gy) {
  __shared__ char SXb[16384];
  __shared__ char Ub[8192];
  __shared__ float2 sX16[2][64];
  int h = blockIdx.x;
  int bs = blockIdx.y * 2;
  int tid = threadIdx.x;
  int w = tid >> 6, lane = tid & 63, lg = lane >> 4, l15 = lane & 15;

  {
    int row = tid >> 2, k0 = (tid & 3) * 16;
    int b = bs + (row >> 5), c = row & 31;
    const float* up = u + ((size_t)(b * Hh + h)) * Ll + c * 64 + k0;
    uint4 v0 = cvt8q(up), v1 = cvt8q(up + 8);
    int base = row * 128 + k0 * 2;
    int swz = (row & 7) << 4;
    *(uint4*)(Ub + (base ^ swz)) = v0;
    *(uint4*)(Ub + ((base + 16) ^ swz)) = v1;
  }
  bf16x8 a1f[2][2];
#pragma unroll
  for (int i = 0; i < 2; ++i) {
    int row = (2 * w + i) * 16 + l15;
#pragma unroll
    for (int kb = 0; kb < 2; ++kb)
      a1f[i][kb] = *(const bf16x8*)(A1 + ((size_t)h * 128 + row) * 64 + kb * 32 + lg * 8);
  }
  __syncthreads();

#pragma unroll
  for (int ct = 0; ct < 4; ++ct) {
    int bc = ct * 16 + l15;
    bf16x8 bu[2];
#pragma unroll
    for (int kb = 0; kb < 2; ++kb)
      bu[kb] = *(const bf16x8*)(Ub + ((bc * 128 + kb * 64 + lg * 16) ^ ((bc & 7) << 4)));
#pragma unroll
    for (int i = 0; i < 2; ++i) {
      f32x4 acc = {0.f, 0.f, 0.f, 0.f};
      acc = __builtin_amdgcn_mfma_f32_16x16x32_bf16(a1f[i][0], bu[0], acc, 0, 0, 0);
      acc = __builtin_amdgcn_mfma_f32_16x16x32_bf16(a1f[i][1], bu[1], acc, 0, 0, 0);
      int n2q = (2 * w + i) * 16 + lg * 4;
      uint2 pk;
      pk.x = f2b(acc[0]) | ((unsigned)f2b(acc[1]) << 16);
      pk.y = f2b(acc[2]) | ((unsigned)f2b(acc[3]) << 16);
      *(uint2*)(SXb + ((bc * 256 + n2q * 2) ^ ((bc & 7) << 4))) = pk;
    }
  }
  __syncthreads();

  bf16x8 a2f[6];
  int rowA = w * 16 + l15;
#pragma unroll
  for (int kb = 0; kb < 6; ++kb)
    a2f[kb] = *(const bf16x8*)(A2 + ((size_t)h * 64 + rowA) * 256 + kb * 32 + lg * 8);

  int nn = tid & 63, bpart = tid >> 6;
  int rbloc = bpart >> 1, rhalf = bpart & 1;
  float lqr = lamQ[h * 128 + 2 * nn], lqi = lamQ[h * 128 + 2 * nn + 1];
  {
    float Xr = 0.f, Xi = 0.f;
    int cbase = rbloc * 32 + rhalf * 16;
    for (int c = 0; c < 16; ++c) {
      int bc = cbase + c;
      int byte = (bc * 256 + 4 * nn) ^ ((bc & 7) << 4);
      unsigned ps = *(const unsigned*)(SXb + byte);
      *(unsigned*)(SXb + byte) = (unsigned)f2b(Xr) | ((unsigned)f2b(Xi) << 16);
      float Sr = b2f((unsigned short)(ps & 0xFFFF));
      float Si = b2f((unsigned short)(ps >> 16));
      float nXr = lqr * Xr - lqi * Xi + Sr;
      float nXi = lqr * Xi + lqi * Xr + Si;
      Xr = nXr;
      Xi = nXi;
    }
    if (rhalf == 0) sX16[rbloc][nn] = make_float2(Xr, Xi);
  }
  __syncthreads();
  if (rhalf) {
    float2 x16 = sX16[rbloc][nn];
    float cr = x16.x, ci = x16.y;
    int cbase = rbloc * 32 + 16;
#pragma unroll
    for (int c = 0; c < 16; ++c) {
      int bc = cbase + c;
      int byte = (bc * 256 + 4 * nn) ^ ((bc & 7) << 4);
      unsigned pv = *(const unsigned*)(SXb + byte);
      float vr = b2f((unsigned short)(pv & 0xFFFF)) + cr;
      float vi = b2f((unsigned short)(pv >> 16)) + ci;
      *(unsigned*)(SXb + byte) = (unsigned)f2b(vr) | ((unsigned)f2b(vi) << 16);
      float t = cr * lqr - ci * lqi;
      ci = cr * lqi + ci * lqr;
      cr = t;
    }
  }
  __syncthreads();

  float Dh = Dv[h];
  int t0 = w * 16 + lg * 4;
  f32x4 acc4[4];
  uint2 usk[4];
#pragma unroll
  for (int ct = 0; ct < 4; ++ct) {
    int bc = ct * 16 + l15;
    f32x4 acc = {0.f, 0.f, 0.f, 0.f};
#pragma unroll
    for (int kb = 0; kb < 2; ++kb) {
      bf16x8 bu = *(const bf16x8*)(Ub + ((bc * 128 + kb * 64 + lg * 16) ^ ((bc & 7) << 4)));
      acc = __builtin_amdgcn_mfma_f32_16x16x32_bf16(a2f[kb], bu, acc, 0, 0, 0);
    }
#pragma unroll
    for (int kb = 2; kb < 6; ++kb) {
      bf16x8 bx = *(const bf16x8*)(SXb + ((bc * 256 + ((kb - 2) * 32 + lg * 8) * 2) ^ ((bc & 7) << 4)));
      acc = __builtin_amdgcn_mfma_f32_16x16x32_bf16(a2f[kb], bx, acc, 0, 0, 0);
    }
    acc4[ct] = acc;
    usk[ct] = *(const uint2*)(Ub + ((bc * 128 + t0 * 2) ^ ((bc & 7) << 4)));
  }
  __syncthreads();

#pragma unroll
  for (int ct = 0; ct < 4; ++ct) {
    int bc = ct * 16 + l15;
    const unsigned short* up = (const unsigned short*)&usk[ct];
    unsigned short e[4];
#pragma unroll
    for (int r = 0; r < 4; ++r) {
      float y = fmaf(Dh, b2f(up[r]), acc4[ct][r]);
      e[r] = f2b(gelu_f(y));
    }
    uint2 pk;
    pk.x = e[0] | ((unsigned)e[1] << 16);
    pk.y = e[2] | ((unsigned)e[3] << 16);
    *(uint2*)(Ub + ((bc * 128 + t0 * 2) ^ ((bc & 7) << 4))) = pk;
  }
  __syncthreads();

#pragma unroll
  for (int i = 0; i < 2; ++i) {
    int j = tid + 256 * i;
    int row = j >> 3, q = j & 7;
    int byte = row * 128 + q * 16;
    uint4 v = *(const uint4*)(Ub + (byte ^ ((row & 7) << 4)));
    int b = bs + (row >> 5), c = row & 31;
    *(uint4*)(gy + ((size_t)(b * Hh + h)) * Ll + c * 64 + q * 8) = v;
  }
}

// ---------------------------------------------------------------------------
// GLU v8 (round-18 version — best measured)
// ---------------------------------------------------------------------------
__global__ __launch_bounds__(512, 4) void glu_kernel(
    const unsigned short* __restrict__ Wimg, const unsigned short* __restrict__ gy,
    const float* __restrict__ bias, float* __restrict__ out) {
  __shared__ char sA[2][2][8192];   // [buf][otl]
  __shared__ char sB[2][8192];
  int lt = blockIdx.x;
  int oz = blockIdx.y;
  int b = lt >> 4, lseg = lt & 15;
  int t = threadIdx.x;
  int lane = t & 63, lg = lane >> 4, l15 = lane & 15;
  int w = t >> 6;
  int otl = w & 1;
  int ot = oz * 2 + otl;
  int wm = (w >> 2) & 1, wn = (w >> 1) & 1;
  int doB = (t < 256);
  int p = (t >> 4) & 15, cg = t & 15;
  const char* Abase0 = (const char*)Wimg + (size_t)(oz * 2) * 131072;
  const char* Abase1 = (const char*)Wimg + (size_t)(oz * 2 + 1) * 131072;
  const unsigned short* gybase = gy + (size_t)b * Hh * Ll + lseg * 128 + cg * 8 + 2 * p * Ll;

  int offA[2], offG[2];
#pragma unroll
  for (int mt = 0; mt < 2; ++mt) {
    int rA = wm * 32 + mt * 16 + l15;
    offA[mt] = rA * 64 + ((lg ^ ((rA >> 1) & 3)) << 4);
    int rG = rA + 64;
    offG[mt] = rG * 64 + ((lg ^ ((rG >> 1) & 3)) << 4);
  }
  int offB[4];
#pragma unroll
  for (int nt = 0; nt < 4; ++nt) {
    int rB = wn * 64 + nt * 16 + l15;
    int pr = ((rB >> 3) << 3) | ((rB & 7) ^ ((rB >> 3) & 7));
    offB[nt] = (lg << 11) + (pr << 4);
  }
  int offW[8];
#pragma unroll
  for (int j = 0; j < 8; ++j) {
    int pr = (cg << 3) | (j ^ (cg & 7));
    offW[j] = ((p >> 2) << 11) + (pr << 4) + ((p & 3) << 2);
  }

  f32x4 accA[2][4], accG[2][4];
#pragma unroll
  for (int mt = 0; mt < 2; ++mt)
#pragma unroll
    for (int nt = 0; nt < 4; ++nt) {
      accA[mt][nt] = (f32x4){0.f, 0.f, 0.f, 0.f};
      accG[mt][nt] = (f32x4){0.f, 0.f, 0.f, 0.f};
    }

  // prologue: stage kt=0 (A both ots via glds; B via reg+ds_write, waves 0-3)
  {
    __builtin_amdgcn_global_load_lds(Abase0 + t * 16, (char*)&sA[0][0][0] + t * 16, 16, 0, 0);
    __builtin_amdgcn_global_load_lds(Abase1 + t * 16, (char*)&sA[0][1][0] + t * 16, 16, 0, 0);
    if (doB) {
      BF8 r0, r1;
      r0.q = *(const uint4*)gybase;
      r1.q = *(const uint4*)(gybase + Ll);
#pragma unroll
      for (int j = 0; j < 8; ++j)
        *(unsigned*)(&sB[0][0] + offW[j]) =
            (unsigned)r0.us[j] | ((unsigned)r1.us[j] << 16);
    }
  }
  __syncthreads();

  for (int kt = 0; kt < 16; ++kt) {
    int cur = kt & 1;
    BF8 r0, r1;
    if (kt < 15) {
      __builtin_amdgcn_global_load_lds(Abase0 + (kt + 1) * 8192 + t * 16,
                                       (char*)&sA[cur ^ 1][0][0] + t * 16, 16, 0, 0);
      __builtin_amdgcn_global_load_lds(Abase1 + (kt + 1) * 8192 + t * 16,
                                       (char*)&sA[cur ^ 1][1][0] + t * 16, 16, 0, 0);
      if (doB) {
        r0.q = *(const uint4*)(gybase + (size_t)(kt + 1) * 32 * Ll);
        r1.q = *(const uint4*)(gybase + (size_t)(kt + 1) * 32 * Ll + Ll);
      }
    }
    const char* bufA = &sA[cur][otl][0];
    const char* bufB = &sB[cur][0];
    bf16x8 aA[2], aG[2], bB[4];
#pragma unroll
    for (int mt = 0; mt < 2; ++mt) {
      aA[mt] = *(const bf16x8*)(bufA + offA[mt]);
      aG[mt] = *(const bf16x8*)(bufA + offG[mt]);
    }
#pragma unroll
    for (int nt = 0; nt < 4; ++nt)
      bB[nt] = *(const bf16x8*)(bufB + offB[nt]);
#pragma unroll
    for (int mt = 0; mt < 2; ++mt)
#pragma unroll
      for (int nt = 0; nt < 4; ++nt) {
        accA[mt][nt] = __builtin_amdgcn_mfma_f32_16x16x32_bf16(bB[nt], aA[mt], accA[mt][nt], 0, 0, 0);
        accG[mt][nt] = __builtin_amdgcn_mfma_f32_16x16x32_bf16(bB[nt], aG[mt], accG[mt][nt], 0, 0, 0);
      }
    if (kt < 15 && doB) {
      char* db = &sB[cur ^ 1][0];
#pragma unroll
      for (int j = 0; j < 8; ++j)
        *(unsigned*)(db + offW[j]) =
            (unsigned)r0.us[j] | ((unsigned)r1.us[j] << 16);
    }
    __syncthreads();
  }

  // epilogue
#pragma unroll
  for (int mt = 0; mt < 2; ++mt) {
    int oA = ot * 64 + wm * 32 + mt * 16 + l15;
    float ba = bias[oA];
    float bg = bias[512 + oA];
    float* orow = out + ((size_t)(b * Hh) + oA) * Ll + lseg * 128 + wn * 64 + lg * 4;
#pragma unroll
    for (int nt = 0; nt < 4; ++nt) {
      float4 res;
      float* rp = (float*)&res;
#pragma unroll
      for (int r = 0; r < 4; ++r) {
        float a = accA[mt][nt][r] + ba;
        float g = accG[mt][nt][r] + bg;
        rp[r] = a * (1.0f / (1.0f + __expf(-g)));
      }
      *(float4*)(orow + nt * 16) = res;
    }
  }
}

// ---------------------------------------------------------------------------
extern "C" void kernel_launch(void* const* d_in, const int* in_sizes, int n_in,
                              void* d_out, int out_size, void* d_ws,
                              size_t ws_size, hipStream_t stream) {
  const float* u      = (const float*)d_in[0];
  const float* C_ri   = (const float*)d_in[1];
  const float* log_dt = (const float*)d_in[2];
  const float* D_v    = (const float*)d_in[3];
  const float* W      = (const float*)d_in[4];
  const float* bias   = (const float*)d_in[5];
  const float* A_ri   = (const float*)d_in[6];
  float* out = (float*)d_out;

  char* ws = (char*)d_ws;
  unsigned short* A1   = (unsigned short*)ws;                // 8 MB
  unsigned short* A2   = (unsigned short*)(ws + 8388608);    // 16 MB
  float*          lamQ = (float*)(ws + 25165824);            // 256 KB
  unsigned short* Wimg = (unsigned short*)(ws + 25427968);   // 1 MB
  unsigned short* gy   = (unsigned short*)(ws + 26476544);   // 16 MB

  prep_kernel<<<640, 512, 0, stream>>>(C_ri, log_dt, A_ri, W, A1, A2, lamQ, Wimg);
  fused_conv_kernel<<<dim3(Hh, 4), 256, 0, stream>>>(u, A1, A2, lamQ, D_v, gy);
  glu_kernel<<<dim3(128, 4), 512, 0, stream>>>(Wimg, gy, bias, out);
}